// Round 6
// baseline (508.693 us; speedup 1.0000x reference)
//
#include <hip/hip_runtime.h>

#define GYD 512
#define GXD 512
#define HD 256
#define WD 256
#define BD 8
#define NSAMP 100000
#define JD 7
#define NCP 9           // padded LDS stride (8 batch columns + 1)
#define NBAND 8
#define CAP 16384       // bucket capacity per band (deterministic counts ~12.5k)

// digit-reverse base 8, 3 digits (involution)
__device__ __forceinline__ int dr3(int i) {
    return ((i & 7) << 6) | (i & 56) | ((i >> 6) & 7);
}

// One radix-8 DIT stage over 8 interleaved 512-pt FFTs in LDS.
template<int LEN, int EIGHTH, int TWSH>
__device__ __forceinline__ void r8_stage(float* __restrict__ re, float* __restrict__ im,
                                         const float* __restrict__ twr,
                                         const float* __restrict__ twi, int g) {
    const int c = g & 7;
    const int m = g >> 3;
    const int off = m & (EIGHTH - 1);
    const int blk = m / EIGHTH;
    const int p0 = (blk * LEN + off) * NCP + c;
    float ar[8], ai[8];
    #pragma unroll
    for (int j = 0; j < 8; ++j) {
        ar[j] = re[p0 + j * EIGHTH * NCP];
        ai[j] = im[p0 + j * EIGHTH * NCP];
    }
    if (TWSH >= 0) {
        #pragma unroll
        for (int j = 1; j < 8; ++j) {
            const int idx = (off * j) << (TWSH >= 0 ? TWSH : 0);
            const float cr = twr[idx], ci = twi[idx];
            const float tr = ar[j] * cr - ai[j] * ci;
            ai[j] = ar[j] * ci + ai[j] * cr;
            ar[j] = tr;
        }
    }
    const float e0r = ar[0] + ar[4], e0i = ai[0] + ai[4];
    const float e1r = ar[0] - ar[4], e1i = ai[0] - ai[4];
    const float e2r = ar[2] + ar[6], e2i = ai[2] + ai[6];
    const float e3r = ar[2] - ar[6], e3i = ai[2] - ai[6];
    const float E0r = e0r + e2r, E0i = e0i + e2i;
    const float E2r = e0r - e2r, E2i = e0i - e2i;
    const float E1r = e1r + e3i, E1i = e1i - e3r;   // e1 - i*e3
    const float E3r = e1r - e3i, E3i = e1i + e3r;   // e1 + i*e3

    const float q0r = ar[1] + ar[5], q0i = ai[1] + ai[5];
    const float q1r = ar[1] - ar[5], q1i = ai[1] - ai[5];
    const float q2r = ar[3] + ar[7], q2i = ai[3] + ai[7];
    const float q3r = ar[3] - ar[7], q3i = ai[3] - ai[7];
    const float O0r = q0r + q2r, O0i = q0i + q2i;
    const float O2r = q0r - q2r, O2i = q0i - q2i;
    const float O1r = q1r + q3i, O1i = q1i - q3r;
    const float O3r = q1r - q3i, O3i = q1i + q3r;

    const float S = 0.70710678118654752f;
    const float T0r = O0r,              T0i = O0i;
    const float T1r = S * (O1r + O1i),  T1i = S * (O1i - O1r);
    const float T2r = O2i,              T2i = -O2r;
    const float T3r = S * (O3i - O3r),  T3i = -S * (O3r + O3i);

    re[p0 + 0 * EIGHTH * NCP] = E0r + T0r;  im[p0 + 0 * EIGHTH * NCP] = E0i + T0i;
    re[p0 + 4 * EIGHTH * NCP] = E0r - T0r;  im[p0 + 4 * EIGHTH * NCP] = E0i - T0i;
    re[p0 + 1 * EIGHTH * NCP] = E1r + T1r;  im[p0 + 1 * EIGHTH * NCP] = E1i + T1i;
    re[p0 + 5 * EIGHTH * NCP] = E1r - T1r;  im[p0 + 5 * EIGHTH * NCP] = E1i - T1i;
    re[p0 + 2 * EIGHTH * NCP] = E2r + T2r;  im[p0 + 2 * EIGHTH * NCP] = E2i + T2i;
    re[p0 + 6 * EIGHTH * NCP] = E2r - T2r;  im[p0 + 6 * EIGHTH * NCP] = E2i - T2i;
    re[p0 + 3 * EIGHTH * NCP] = E3r + T3r;  im[p0 + 3 * EIGHTH * NCP] = E3i + T3i;
    re[p0 + 7 * EIGHTH * NCP] = E3r - T3r;  im[p0 + 7 * EIGHTH * NCP] = E3i - T3i;
}

// Bucketing kernel 1: zero the 8 band cursors (ws is re-poisoned each call).
__global__ void zero_kernel(int* __restrict__ cursor) {
    if (threadIdx.x < NBAND) cursor[threadIdx.x] = 0;
}

// Bucketing kernel 2: scatter sample ids into per-band buckets by center row.
__global__ __launch_bounds__(256) void scatter_kernel(
    const int* __restrict__ iy, int* __restrict__ bucket, int* __restrict__ cursor) {
    const int n = blockIdx.x * 256 + threadIdx.x;
    if (n >= NSAMP) return;
    const int band = iy[n * JD + 3] >> 6;          // center row / 64
    const int slot = atomicAdd(&cursor[band], 1);
    bucket[band * CAP + slot] = n;
}

// Kernel A: apodized zero-padded row FFT for ALL 8 batches of one y row.
__global__ __launch_bounds__(512) void rowfft_kernel(
    const float* __restrict__ xr, const float* __restrict__ xi,
    const float* __restrict__ sc_y, const float* __restrict__ sc_x,
    float4* __restrict__ G1i4)
{
    __shared__ float re[512 * NCP];
    __shared__ float im[512 * NCP];
    __shared__ float twr[512];
    __shared__ float twi[512];
    const int t = threadIdx.x;
    const int y = blockIdx.x;

    {   // tw[m] = exp(-2*pi*i*m/512)
        float sn, cs;
        sincospif(-(float)t / 256.0f, &sn, &cs);
        twr[t] = cs; twi[t] = sn;
    }

    const float sy = sc_y[y];
    {
        const int b = t >> 6;               // 0..7
        const int x4 = (t & 63) << 2;       // 0..252 step 4
        const float4 vr = *(const float4*)(xr + b * (HD * WD) + y * WD + x4);
        const float4 vi = *(const float4*)(xi + b * (HD * WD) + y * WD + x4);
        const float4 sx = *(const float4*)(sc_x + x4);
        int p;
        float s;
        s = sy * sx.x; p = dr3(x4 + 0) * NCP + b; re[p] = vr.x * s; im[p] = vi.x * s;
        s = sy * sx.y; p = dr3(x4 + 1) * NCP + b; re[p] = vr.y * s; im[p] = vi.y * s;
        s = sy * sx.z; p = dr3(x4 + 2) * NCP + b; re[p] = vr.z * s; im[p] = vi.z * s;
        s = sy * sx.w; p = dr3(x4 + 3) * NCP + b; re[p] = vr.w * s; im[p] = vi.w * s;
        #pragma unroll
        for (int k = 0; k < 4; ++k) {       // x zero-pad 256..511
            p = dr3(x4 + 256 + k) * NCP + b;
            re[p] = 0.0f; im[p] = 0.0f;
        }
    }
    __syncthreads();
    r8_stage<8, 1, -1>(re, im, twr, twi, t);
    __syncthreads();
    r8_stage<64, 8, 3>(re, im, twr, twi, t);
    __syncthreads();
    r8_stage<512, 64, 0>(re, im, twr, twi, t);
    __syncthreads();

    float4* dst = G1i4 + (size_t)y * 2048;
    #pragma unroll
    for (int iter = 0; iter < 4; ++iter) {
        const int if4 = iter * 512 + t;      // 0..2047
        const int x = if4 >> 2;
        const int b = (if4 & 3) << 1;
        const int p = x * NCP + b;
        dst[if4] = make_float4(re[p], im[p], re[p + 1], im[p + 1]);
    }
}

// Kernel B: zero-padded column FFT for ALL 8 batches of one x column.
__global__ __launch_bounds__(512) void colfft_kernel(
    const float4* __restrict__ G1i4, float4* __restrict__ ghat4)
{
    __shared__ float re[512 * NCP];
    __shared__ float im[512 * NCP];
    __shared__ float twr[512];
    __shared__ float twi[512];
    const int t = threadIdx.x;
    const int x = blockIdx.x;

    {
        float sn, cs;
        sincospif(-(float)t / 256.0f, &sn, &cs);
        twr[t] = cs; twi[t] = sn;
    }

    #pragma unroll
    for (int iter = 0; iter < 2; ++iter) {
        const int i = iter * 512 + t;        // 0..1023
        const int yy = i >> 2;               // 0..255
        const int bp = (i & 3) << 1;
        const float4 v = G1i4[((size_t)yy * GXD + x) * 4 + (i & 3)];
        const int p = dr3(yy) * NCP + bp;
        re[p] = v.x; im[p] = v.y; re[p + 1] = v.z; im[p + 1] = v.w;
        const int p2 = dr3(yy + 256) * NCP + bp;   // y zero-pad
        re[p2] = 0.0f; im[p2] = 0.0f; re[p2 + 1] = 0.0f; im[p2 + 1] = 0.0f;
    }
    __syncthreads();
    r8_stage<8, 1, -1>(re, im, twr, twi, t);
    __syncthreads();
    r8_stage<64, 8, 3>(re, im, twr, twi, t);
    __syncthreads();
    r8_stage<512, 64, 0>(re, im, twr, twi, t);
    __syncthreads();

    const float scale = 1.0f / 512.0f;       // ortho: 1/sqrt(512*512)
    #pragma unroll
    for (int iter = 0; iter < 4; ++iter) {
        const int if4 = iter * 512 + t;      // 0..2047
        const int yy = if4 >> 2;             // 0..511
        const int b = (if4 & 3) << 1;
        const int p = yy * NCP + b;
        ghat4[((size_t)yy * GXD + x) * 4 + (if4 & 3)] =
            make_float4(re[p] * scale, im[p] * scale,
                        re[p + 1] * scale, im[p + 1] * scale);
    }
}

// Kernel C: bucketed 7x7 KB gather on interleaved ghat2.
// blockIdx&7 = band -> XCD pinning (SPX round-robin): each XCD's gather
// working set is its band's 2.3 MB slab -> L2-resident.
// Block = 32 samples x 8 batches; per tap the 8 b-lanes read one 64 B line.
__global__ __launch_bounds__(256) void gather_kernel(
    const float2* __restrict__ ghat2,
    const float* __restrict__ wy, const float* __restrict__ wx,
    const float* __restrict__ phr, const float* __restrict__ phi,
    const int* __restrict__ iy, const int* __restrict__ ix,
    const int* __restrict__ bucket, const int* __restrict__ cursor,
    float2* __restrict__ out)
{
    const int band = blockIdx.x & 7;
    const int grp = blockIdx.x >> 3;         // 0..511
    const int cnt = cursor[band];
    const int s0 = grp * 32;
    if (s0 >= cnt) return;

    __shared__ int   s_id[32];
    __shared__ int   s_iy[32 * JD];
    __shared__ int   s_ix[32 * JD];
    __shared__ float s_wy[32 * JD];
    __shared__ float s_wx[32 * JD];
    __shared__ float s_pr[32];
    __shared__ float s_pi[32];
    const int t = threadIdx.x;

    if (t < 32) s_id[t] = (s0 + t < cnt) ? bucket[band * CAP + s0 + t] : -1;
    __syncthreads();

    if (t < 224) {                           // 32 samples x 7 taps
        const int s = t / 7;
        const int j = t - s * 7;
        const int id = s_id[s];
        if (id >= 0) {
            const int g = id * JD + j;
            s_iy[t] = iy[g];
            s_ix[t] = ix[g];
            s_wy[t] = wy[g];
            s_wx[t] = wx[g];
        } else {
            s_iy[t] = 0; s_ix[t] = 0; s_wy[t] = 0.0f; s_wx[t] = 0.0f;
        }
    } else {                                 // threads 224..255: phase
        const int s = t - 224;
        const int id = s_id[s];
        s_pr[s] = (id >= 0) ? phr[id] : 0.0f;
        s_pi[s] = (id >= 0) ? phi[id] : 0.0f;
    }
    __syncthreads();

    const int b = t & 7;
    const int s = t >> 3;                    // local sample 0..31
    const int base = s * JD;

    int iyl[JD], ixl[JD];
    float wyl[JD], wxl[JD];
    #pragma unroll
    for (int j = 0; j < JD; ++j) {
        iyl[j] = s_iy[base + j];
        ixl[j] = s_ix[base + j];
        wyl[j] = s_wy[base + j];
        wxl[j] = s_wx[base + j];
    }

    float ar = 0.0f, ai = 0.0f;
    #pragma unroll
    for (int j = 0; j < JD; ++j) {
        const int rowoff = iyl[j] * GXD;
        const float wj = wyl[j];
        #pragma unroll
        for (int k = 0; k < JD; ++k) {
            const float w = wj * wxl[k];
            const float2 v = ghat2[(size_t)(rowoff + ixl[k]) * BD + b];
            ar += v.x * w;
            ai += v.y * w;
        }
    }

    const int id = s_id[s];
    if (id >= 0) {
        const float pr = s_pr[s], pi = s_pi[s];
        out[(size_t)b * NSAMP + id] = make_float2(ar * pr - ai * pi,
                                                  ar * pi + ai * pr);
    }
}

extern "C" void kernel_launch(void* const* d_in, const int* in_sizes, int n_in,
                              void* d_out, int out_size, void* d_ws, size_t ws_size,
                              hipStream_t stream) {
    const float* xr   = (const float*)d_in[0];
    const float* xi   = (const float*)d_in[1];
    const float* sc_y = (const float*)d_in[2];
    const float* sc_x = (const float*)d_in[3];
    const float* wy   = (const float*)d_in[4];
    const float* wx   = (const float*)d_in[5];
    const float* phr  = (const float*)d_in[6];
    const float* phi  = (const float*)d_in[7];
    const int*   iy   = (const int*)d_in[8];
    const int*   ix   = (const int*)d_in[9];

    // Workspace: G1i (8.39 MB) | ghat2 (16.78 MB) | bucket (512 KB) | cursor (32 B)
    char* ws = (char*)d_ws;
    float4* G1i4   = (float4*)ws;
    float4* ghat4  = (float4*)(ws + (size_t)HD * GXD * BD * sizeof(float2));
    int*    bucket = (int*)(ws + (size_t)(HD + GYD) * GXD * BD * sizeof(float2));
    int*    cursor = bucket + NBAND * CAP;

    zero_kernel<<<1, 64, 0, stream>>>(cursor);
    scatter_kernel<<<(NSAMP + 255) / 256, 256, 0, stream>>>(iy, bucket, cursor);
    rowfft_kernel<<<HD, 512, 0, stream>>>(xr, xi, sc_y, sc_x, G1i4);
    colfft_kernel<<<GXD, 512, 0, stream>>>(G1i4, ghat4);
    gather_kernel<<<NBAND * (CAP / 32), 256, 0, stream>>>(
        (const float2*)ghat4, wy, wx, phr, phi, iy, ix, bucket, cursor,
        (float2*)d_out);
}

// Round 7
// 135.321 us; speedup vs baseline: 3.7591x; 3.7591x over previous
//
#include <hip/hip_runtime.h>

#define GYD 512
#define GXD 512
#define HD 256
#define WD 256
#define BD 8
#define NSAMP 100000
#define JD 7
#define NCP 9           // padded LDS stride (8 batch columns + 1)
#define NBAND 8
#define CAP 16384       // bucket capacity per band (deterministic counts ~12.5k)
#define SCHUNK 1024     // samples per scatter block

// digit-reverse base 8, 3 digits (involution)
__device__ __forceinline__ int dr3(int i) {
    return ((i & 7) << 6) | (i & 56) | ((i >> 6) & 7);
}

// One radix-8 DIT stage over 8 interleaved 512-pt FFTs in LDS.
template<int LEN, int EIGHTH, int TWSH>
__device__ __forceinline__ void r8_stage(float* __restrict__ re, float* __restrict__ im,
                                         const float* __restrict__ twr,
                                         const float* __restrict__ twi, int g) {
    const int c = g & 7;
    const int m = g >> 3;
    const int off = m & (EIGHTH - 1);
    const int blk = m / EIGHTH;
    const int p0 = (blk * LEN + off) * NCP + c;
    float ar[8], ai[8];
    #pragma unroll
    for (int j = 0; j < 8; ++j) {
        ar[j] = re[p0 + j * EIGHTH * NCP];
        ai[j] = im[p0 + j * EIGHTH * NCP];
    }
    if (TWSH >= 0) {
        #pragma unroll
        for (int j = 1; j < 8; ++j) {
            const int idx = (off * j) << (TWSH >= 0 ? TWSH : 0);
            const float cr = twr[idx], ci = twi[idx];
            const float tr = ar[j] * cr - ai[j] * ci;
            ai[j] = ar[j] * ci + ai[j] * cr;
            ar[j] = tr;
        }
    }
    const float e0r = ar[0] + ar[4], e0i = ai[0] + ai[4];
    const float e1r = ar[0] - ar[4], e1i = ai[0] - ai[4];
    const float e2r = ar[2] + ar[6], e2i = ai[2] + ai[6];
    const float e3r = ar[2] - ar[6], e3i = ai[2] - ai[6];
    const float E0r = e0r + e2r, E0i = e0i + e2i;
    const float E2r = e0r - e2r, E2i = e0i - e2i;
    const float E1r = e1r + e3i, E1i = e1i - e3r;   // e1 - i*e3
    const float E3r = e1r - e3i, E3i = e1i + e3r;   // e1 + i*e3

    const float q0r = ar[1] + ar[5], q0i = ai[1] + ai[5];
    const float q1r = ar[1] - ar[5], q1i = ai[1] - ai[5];
    const float q2r = ar[3] + ar[7], q2i = ai[3] + ai[7];
    const float q3r = ar[3] - ar[7], q3i = ai[3] - ai[7];
    const float O0r = q0r + q2r, O0i = q0i + q2i;
    const float O2r = q0r - q2r, O2i = q0i - q2i;
    const float O1r = q1r + q3i, O1i = q1i - q3r;
    const float O3r = q1r - q3i, O3i = q1i + q3r;

    const float S = 0.70710678118654752f;
    const float T0r = O0r,              T0i = O0i;
    const float T1r = S * (O1r + O1i),  T1i = S * (O1i - O1r);
    const float T2r = O2i,              T2i = -O2r;
    const float T3r = S * (O3i - O3r),  T3i = -S * (O3r + O3i);

    re[p0 + 0 * EIGHTH * NCP] = E0r + T0r;  im[p0 + 0 * EIGHTH * NCP] = E0i + T0i;
    re[p0 + 4 * EIGHTH * NCP] = E0r - T0r;  im[p0 + 4 * EIGHTH * NCP] = E0i - T0i;
    re[p0 + 1 * EIGHTH * NCP] = E1r + T1r;  im[p0 + 1 * EIGHTH * NCP] = E1i + T1i;
    re[p0 + 5 * EIGHTH * NCP] = E1r - T1r;  im[p0 + 5 * EIGHTH * NCP] = E1i - T1i;
    re[p0 + 2 * EIGHTH * NCP] = E2r + T2r;  im[p0 + 2 * EIGHTH * NCP] = E2i + T2i;
    re[p0 + 6 * EIGHTH * NCP] = E2r - T2r;  im[p0 + 6 * EIGHTH * NCP] = E2i - T2i;
    re[p0 + 3 * EIGHTH * NCP] = E3r + T3r;  im[p0 + 3 * EIGHTH * NCP] = E3i + T3i;
    re[p0 + 7 * EIGHTH * NCP] = E3r - T3r;  im[p0 + 7 * EIGHTH * NCP] = E3i - T3i;
}

// Bucketing kernel 1: zero the 8 band cursors (ws is re-poisoned each call).
__global__ void zero_kernel(int* __restrict__ cursor) {
    if (threadIdx.x < NBAND) cursor[threadIdx.x] = 0;
}

// Bucketing kernel 2: two-phase scatter. Block ranks SCHUNK samples in an LDS
// histogram (fast LDS atomics), reserves one contiguous range per band with a
// single global atomicAdd (8 per block, 784 total vs 100k in R6), then writes
// conflict-free.
__global__ __launch_bounds__(256) void scatter_kernel(
    const int* __restrict__ iy, int* __restrict__ bucket, int* __restrict__ cursor) {
    __shared__ int cnt[NBAND];
    __shared__ int base[NBAND];
    const int t = threadIdx.x;
    const int n0 = blockIdx.x * SCHUNK;
    if (t < NBAND) cnt[t] = 0;
    __syncthreads();

    int band[SCHUNK / 256], local[SCHUNK / 256];
    #pragma unroll
    for (int k = 0; k < SCHUNK / 256; ++k) {
        const int n = n0 + k * 256 + t;
        band[k] = -1;
        if (n < NSAMP) {
            band[k] = iy[n * JD + 3] >> 6;       // center row / 64
            local[k] = atomicAdd(&cnt[band[k]], 1);
        }
    }
    __syncthreads();
    if (t < NBAND) base[t] = atomicAdd(&cursor[t], cnt[t]);
    __syncthreads();
    #pragma unroll
    for (int k = 0; k < SCHUNK / 256; ++k) {
        const int n = n0 + k * 256 + t;
        if (band[k] >= 0)
            bucket[band[k] * CAP + base[band[k]] + local[k]] = n;
    }
}

// Kernel A: apodized zero-padded row FFT for ALL 8 batches of one y row.
__global__ __launch_bounds__(512) void rowfft_kernel(
    const float* __restrict__ xr, const float* __restrict__ xi,
    const float* __restrict__ sc_y, const float* __restrict__ sc_x,
    float4* __restrict__ G1i4)
{
    __shared__ float re[512 * NCP];
    __shared__ float im[512 * NCP];
    __shared__ float twr[512];
    __shared__ float twi[512];
    const int t = threadIdx.x;
    const int y = blockIdx.x;

    {   // tw[m] = exp(-2*pi*i*m/512)
        float sn, cs;
        sincospif(-(float)t / 256.0f, &sn, &cs);
        twr[t] = cs; twi[t] = sn;
    }

    const float sy = sc_y[y];
    {
        const int b = t >> 6;               // 0..7
        const int x4 = (t & 63) << 2;       // 0..252 step 4
        const float4 vr = *(const float4*)(xr + b * (HD * WD) + y * WD + x4);
        const float4 vi = *(const float4*)(xi + b * (HD * WD) + y * WD + x4);
        const float4 sx = *(const float4*)(sc_x + x4);
        int p;
        float s;
        s = sy * sx.x; p = dr3(x4 + 0) * NCP + b; re[p] = vr.x * s; im[p] = vi.x * s;
        s = sy * sx.y; p = dr3(x4 + 1) * NCP + b; re[p] = vr.y * s; im[p] = vi.y * s;
        s = sy * sx.z; p = dr3(x4 + 2) * NCP + b; re[p] = vr.z * s; im[p] = vi.z * s;
        s = sy * sx.w; p = dr3(x4 + 3) * NCP + b; re[p] = vr.w * s; im[p] = vi.w * s;
        #pragma unroll
        for (int k = 0; k < 4; ++k) {       // x zero-pad 256..511
            p = dr3(x4 + 256 + k) * NCP + b;
            re[p] = 0.0f; im[p] = 0.0f;
        }
    }
    __syncthreads();
    r8_stage<8, 1, -1>(re, im, twr, twi, t);
    __syncthreads();
    r8_stage<64, 8, 3>(re, im, twr, twi, t);
    __syncthreads();
    r8_stage<512, 64, 0>(re, im, twr, twi, t);
    __syncthreads();

    float4* dst = G1i4 + (size_t)y * 2048;
    #pragma unroll
    for (int iter = 0; iter < 4; ++iter) {
        const int if4 = iter * 512 + t;      // 0..2047
        const int x = if4 >> 2;
        const int b = (if4 & 3) << 1;
        const int p = x * NCP + b;
        dst[if4] = make_float4(re[p], im[p], re[p + 1], im[p + 1]);
    }
}

// Kernel B: zero-padded column FFT for ALL 8 batches of one x column.
__global__ __launch_bounds__(512) void colfft_kernel(
    const float4* __restrict__ G1i4, float4* __restrict__ ghat4)
{
    __shared__ float re[512 * NCP];
    __shared__ float im[512 * NCP];
    __shared__ float twr[512];
    __shared__ float twi[512];
    const int t = threadIdx.x;
    const int x = blockIdx.x;

    {
        float sn, cs;
        sincospif(-(float)t / 256.0f, &sn, &cs);
        twr[t] = cs; twi[t] = sn;
    }

    #pragma unroll
    for (int iter = 0; iter < 2; ++iter) {
        const int i = iter * 512 + t;        // 0..1023
        const int yy = i >> 2;               // 0..255
        const int bp = (i & 3) << 1;
        const float4 v = G1i4[((size_t)yy * GXD + x) * 4 + (i & 3)];
        const int p = dr3(yy) * NCP + bp;
        re[p] = v.x; im[p] = v.y; re[p + 1] = v.z; im[p + 1] = v.w;
        const int p2 = dr3(yy + 256) * NCP + bp;   // y zero-pad
        re[p2] = 0.0f; im[p2] = 0.0f; re[p2 + 1] = 0.0f; im[p2 + 1] = 0.0f;
    }
    __syncthreads();
    r8_stage<8, 1, -1>(re, im, twr, twi, t);
    __syncthreads();
    r8_stage<64, 8, 3>(re, im, twr, twi, t);
    __syncthreads();
    r8_stage<512, 64, 0>(re, im, twr, twi, t);
    __syncthreads();

    const float scale = 1.0f / 512.0f;       // ortho: 1/sqrt(512*512)
    #pragma unroll
    for (int iter = 0; iter < 4; ++iter) {
        const int if4 = iter * 512 + t;      // 0..2047
        const int yy = if4 >> 2;             // 0..511
        const int b = (if4 & 3) << 1;
        const int p = yy * NCP + b;
        ghat4[((size_t)yy * GXD + x) * 4 + (if4 & 3)] =
            make_float4(re[p] * scale, im[p] * scale,
                        re[p + 1] * scale, im[p + 1] * scale);
    }
}

// Kernel C: bucketed 7x7 KB gather on interleaved ghat2.
// blockIdx&7 = band -> XCD pinning (SPX round-robin): each XCD's gather
// working set is its band's ~2.3 MB slab -> L2-resident.
// Block = 32 samples x 8 batches; per tap the 8 b-lanes read one 64 B line.
__global__ __launch_bounds__(256) void gather_kernel(
    const float2* __restrict__ ghat2,
    const float* __restrict__ wy, const float* __restrict__ wx,
    const float* __restrict__ phr, const float* __restrict__ phi,
    const int* __restrict__ iy, const int* __restrict__ ix,
    const int* __restrict__ bucket, const int* __restrict__ cursor,
    float2* __restrict__ out)
{
    const int band = blockIdx.x & 7;
    const int grp = blockIdx.x >> 3;         // 0..511
    const int cnt = cursor[band];
    const int s0 = grp * 32;
    if (s0 >= cnt) return;

    __shared__ int   s_id[32];
    __shared__ int   s_iy[32 * JD];
    __shared__ int   s_ix[32 * JD];
    __shared__ float s_wy[32 * JD];
    __shared__ float s_wx[32 * JD];
    __shared__ float s_pr[32];
    __shared__ float s_pi[32];
    const int t = threadIdx.x;

    if (t < 32) s_id[t] = (s0 + t < cnt) ? bucket[band * CAP + s0 + t] : -1;
    __syncthreads();

    if (t < 224) {                           // 32 samples x 7 taps
        const int s = t / 7;
        const int j = t - s * 7;
        const int id = s_id[s];
        if (id >= 0) {
            const int g = id * JD + j;
            s_iy[t] = iy[g];
            s_ix[t] = ix[g];
            s_wy[t] = wy[g];
            s_wx[t] = wx[g];
        } else {
            s_iy[t] = 0; s_ix[t] = 0; s_wy[t] = 0.0f; s_wx[t] = 0.0f;
        }
    } else {                                 // threads 224..255: phase
        const int s = t - 224;
        const int id = s_id[s];
        s_pr[s] = (id >= 0) ? phr[id] : 0.0f;
        s_pi[s] = (id >= 0) ? phi[id] : 0.0f;
    }
    __syncthreads();

    const int b = t & 7;
    const int s = t >> 3;                    // local sample 0..31
    const int base = s * JD;

    int iyl[JD], ixl[JD];
    float wyl[JD], wxl[JD];
    #pragma unroll
    for (int j = 0; j < JD; ++j) {
        iyl[j] = s_iy[base + j];
        ixl[j] = s_ix[base + j];
        wyl[j] = s_wy[base + j];
        wxl[j] = s_wx[base + j];
    }

    float ar = 0.0f, ai = 0.0f;
    #pragma unroll
    for (int j = 0; j < JD; ++j) {
        const int rowoff = iyl[j] * GXD;
        const float wj = wyl[j];
        #pragma unroll
        for (int k = 0; k < JD; ++k) {
            const float w = wj * wxl[k];
            const float2 v = ghat2[(size_t)(rowoff + ixl[k]) * BD + b];
            ar += v.x * w;
            ai += v.y * w;
        }
    }

    const int id = s_id[s];
    if (id >= 0) {
        const float pr = s_pr[s], pi = s_pi[s];
        out[(size_t)b * NSAMP + id] = make_float2(ar * pr - ai * pi,
                                                  ar * pi + ai * pr);
    }
}

extern "C" void kernel_launch(void* const* d_in, const int* in_sizes, int n_in,
                              void* d_out, int out_size, void* d_ws, size_t ws_size,
                              hipStream_t stream) {
    const float* xr   = (const float*)d_in[0];
    const float* xi   = (const float*)d_in[1];
    const float* sc_y = (const float*)d_in[2];
    const float* sc_x = (const float*)d_in[3];
    const float* wy   = (const float*)d_in[4];
    const float* wx   = (const float*)d_in[5];
    const float* phr  = (const float*)d_in[6];
    const float* phi  = (const float*)d_in[7];
    const int*   iy   = (const int*)d_in[8];
    const int*   ix   = (const int*)d_in[9];

    // Workspace: G1i (8.39 MB) | ghat2 (16.78 MB) | bucket (512 KB) | cursor (32 B)
    char* ws = (char*)d_ws;
    float4* G1i4   = (float4*)ws;
    float4* ghat4  = (float4*)(ws + (size_t)HD * GXD * BD * sizeof(float2));
    int*    bucket = (int*)(ws + (size_t)(HD + GYD) * GXD * BD * sizeof(float2));
    int*    cursor = bucket + NBAND * CAP;

    zero_kernel<<<1, 64, 0, stream>>>(cursor);
    scatter_kernel<<<(NSAMP + SCHUNK - 1) / SCHUNK, 256, 0, stream>>>(iy, bucket, cursor);
    rowfft_kernel<<<HD, 512, 0, stream>>>(xr, xi, sc_y, sc_x, G1i4);
    colfft_kernel<<<GXD, 512, 0, stream>>>(G1i4, ghat4);
    gather_kernel<<<NBAND * (CAP / 32), 256, 0, stream>>>(
        (const float2*)ghat4, wy, wx, phr, phi, iy, ix, bucket, cursor,
        (float2*)d_out);
}

// Round 8
// 114.089 us; speedup vs baseline: 4.4587x; 1.1861x over previous
//
#include <hip/hip_runtime.h>
#include <hip/hip_fp16.h>

#define GYD 512
#define GXD 512
#define HD 256
#define WD 256
#define BD 8
#define NSAMP 100000
#define JD 7
#define NCP 9           // padded LDS stride (8 batch columns + 1)

// digit-reverse base 8, 3 digits (involution)
__device__ __forceinline__ int dr3(int i) {
    return ((i & 7) << 6) | (i & 56) | ((i >> 6) & 7);
}

// One radix-8 DIT stage over 8 interleaved 512-pt FFTs in LDS.
template<int LEN, int EIGHTH, int TWSH>
__device__ __forceinline__ void r8_stage(float* __restrict__ re, float* __restrict__ im,
                                         const float* __restrict__ twr,
                                         const float* __restrict__ twi, int g) {
    const int c = g & 7;
    const int m = g >> 3;
    const int off = m & (EIGHTH - 1);
    const int blk = m / EIGHTH;
    const int p0 = (blk * LEN + off) * NCP + c;
    float ar[8], ai[8];
    #pragma unroll
    for (int j = 0; j < 8; ++j) {
        ar[j] = re[p0 + j * EIGHTH * NCP];
        ai[j] = im[p0 + j * EIGHTH * NCP];
    }
    if (TWSH >= 0) {
        #pragma unroll
        for (int j = 1; j < 8; ++j) {
            const int idx = (off * j) << (TWSH >= 0 ? TWSH : 0);
            const float cr = twr[idx], ci = twi[idx];
            const float tr = ar[j] * cr - ai[j] * ci;
            ai[j] = ar[j] * ci + ai[j] * cr;
            ar[j] = tr;
        }
    }
    const float e0r = ar[0] + ar[4], e0i = ai[0] + ai[4];
    const float e1r = ar[0] - ar[4], e1i = ai[0] - ai[4];
    const float e2r = ar[2] + ar[6], e2i = ai[2] + ai[6];
    const float e3r = ar[2] - ar[6], e3i = ai[2] - ai[6];
    const float E0r = e0r + e2r, E0i = e0i + e2i;
    const float E2r = e0r - e2r, E2i = e0i - e2i;
    const float E1r = e1r + e3i, E1i = e1i - e3r;   // e1 - i*e3
    const float E3r = e1r - e3i, E3i = e1i + e3r;   // e1 + i*e3

    const float q0r = ar[1] + ar[5], q0i = ai[1] + ai[5];
    const float q1r = ar[1] - ar[5], q1i = ai[1] - ai[5];
    const float q2r = ar[3] + ar[7], q2i = ai[3] + ai[7];
    const float q3r = ar[3] - ar[7], q3i = ai[3] - ai[7];
    const float O0r = q0r + q2r, O0i = q0i + q2i;
    const float O2r = q0r - q2r, O2i = q0i - q2i;
    const float O1r = q1r + q3i, O1i = q1i - q3r;
    const float O3r = q1r - q3i, O3i = q1i + q3r;

    const float S = 0.70710678118654752f;
    const float T0r = O0r,              T0i = O0i;
    const float T1r = S * (O1r + O1i),  T1i = S * (O1i - O1r);
    const float T2r = O2i,              T2i = -O2r;
    const float T3r = S * (O3i - O3r),  T3i = -S * (O3r + O3i);

    re[p0 + 0 * EIGHTH * NCP] = E0r + T0r;  im[p0 + 0 * EIGHTH * NCP] = E0i + T0i;
    re[p0 + 4 * EIGHTH * NCP] = E0r - T0r;  im[p0 + 4 * EIGHTH * NCP] = E0i - T0i;
    re[p0 + 1 * EIGHTH * NCP] = E1r + T1r;  im[p0 + 1 * EIGHTH * NCP] = E1i + T1i;
    re[p0 + 5 * EIGHTH * NCP] = E1r - T1r;  im[p0 + 5 * EIGHTH * NCP] = E1i - T1i;
    re[p0 + 2 * EIGHTH * NCP] = E2r + T2r;  im[p0 + 2 * EIGHTH * NCP] = E2i + T2i;
    re[p0 + 6 * EIGHTH * NCP] = E2r - T2r;  im[p0 + 6 * EIGHTH * NCP] = E2i - T2i;
    re[p0 + 3 * EIGHTH * NCP] = E3r + T3r;  im[p0 + 3 * EIGHTH * NCP] = E3i + T3i;
    re[p0 + 7 * EIGHTH * NCP] = E3r - T3r;  im[p0 + 7 * EIGHTH * NCP] = E3i - T3i;
}

// Kernel A: apodized zero-padded row FFT for ALL 8 batches of one y row.
// Output G1i (fp32, batch-interleaved) -- fully coalesced float4 stores.
__global__ __launch_bounds__(512) void rowfft_kernel(
    const float* __restrict__ xr, const float* __restrict__ xi,
    const float* __restrict__ sc_y, const float* __restrict__ sc_x,
    float4* __restrict__ G1i4)
{
    __shared__ float re[512 * NCP];
    __shared__ float im[512 * NCP];
    __shared__ float twr[512];
    __shared__ float twi[512];
    const int t = threadIdx.x;
    const int y = blockIdx.x;

    {   // tw[m] = exp(-2*pi*i*m/512)
        float sn, cs;
        sincospif(-(float)t / 256.0f, &sn, &cs);
        twr[t] = cs; twi[t] = sn;
    }

    const float sy = sc_y[y];
    {
        const int b = t >> 6;               // 0..7
        const int x4 = (t & 63) << 2;       // 0..252 step 4
        const float4 vr = *(const float4*)(xr + b * (HD * WD) + y * WD + x4);
        const float4 vi = *(const float4*)(xi + b * (HD * WD) + y * WD + x4);
        const float4 sx = *(const float4*)(sc_x + x4);
        int p;
        float s;
        s = sy * sx.x; p = dr3(x4 + 0) * NCP + b; re[p] = vr.x * s; im[p] = vi.x * s;
        s = sy * sx.y; p = dr3(x4 + 1) * NCP + b; re[p] = vr.y * s; im[p] = vi.y * s;
        s = sy * sx.z; p = dr3(x4 + 2) * NCP + b; re[p] = vr.z * s; im[p] = vi.z * s;
        s = sy * sx.w; p = dr3(x4 + 3) * NCP + b; re[p] = vr.w * s; im[p] = vi.w * s;
        #pragma unroll
        for (int k = 0; k < 4; ++k) {       // x zero-pad 256..511
            p = dr3(x4 + 256 + k) * NCP + b;
            re[p] = 0.0f; im[p] = 0.0f;
        }
    }
    __syncthreads();
    r8_stage<8, 1, -1>(re, im, twr, twi, t);
    __syncthreads();
    r8_stage<64, 8, 3>(re, im, twr, twi, t);
    __syncthreads();
    r8_stage<512, 64, 0>(re, im, twr, twi, t);
    __syncthreads();

    float4* dst = G1i4 + (size_t)y * 2048;
    #pragma unroll
    for (int iter = 0; iter < 4; ++iter) {
        const int if4 = iter * 512 + t;      // 0..2047
        const int x = if4 >> 2;
        const int b = (if4 & 3) << 1;
        const int p = x * NCP + b;
        dst[if4] = make_float4(re[p], im[p], re[p + 1], im[p + 1]);
    }
}

// Kernel B: zero-padded column FFT for ALL 8 batches of one x column.
// Output ghat in FP16 batch-interleaved: ghat_h[(y*512+x)*8 + b] = half2(re,im).
// A grid point = 32 B; a sample's 7 consecutive x-taps = 224 contiguous bytes.
__global__ __launch_bounds__(512) void colfft_kernel(
    const float4* __restrict__ G1i4, float2* __restrict__ ghat_f2)
{
    __shared__ float re[512 * NCP];
    __shared__ float im[512 * NCP];
    __shared__ float twr[512];
    __shared__ float twi[512];
    const int t = threadIdx.x;
    const int x = blockIdx.x;

    {
        float sn, cs;
        sincospif(-(float)t / 256.0f, &sn, &cs);
        twr[t] = cs; twi[t] = sn;
    }

    #pragma unroll
    for (int iter = 0; iter < 2; ++iter) {
        const int i = iter * 512 + t;        // 0..1023
        const int yy = i >> 2;               // 0..255
        const int bp = (i & 3) << 1;
        const float4 v = G1i4[((size_t)yy * GXD + x) * 4 + (i & 3)];
        const int p = dr3(yy) * NCP + bp;
        re[p] = v.x; im[p] = v.y; re[p + 1] = v.z; im[p + 1] = v.w;
        const int p2 = dr3(yy + 256) * NCP + bp;   // y zero-pad
        re[p2] = 0.0f; im[p2] = 0.0f; re[p2 + 1] = 0.0f; im[p2 + 1] = 0.0f;
    }
    __syncthreads();
    r8_stage<8, 1, -1>(re, im, twr, twi, t);
    __syncthreads();
    r8_stage<64, 8, 3>(re, im, twr, twi, t);
    __syncthreads();
    r8_stage<512, 64, 0>(re, im, twr, twi, t);
    __syncthreads();

    const float scale = 1.0f / 512.0f;       // ortho: 1/sqrt(512*512)
    #pragma unroll
    for (int iter = 0; iter < 4; ++iter) {
        const int if4 = iter * 512 + t;      // 0..2047
        const int yy = if4 >> 2;             // 0..511
        const int b = (if4 & 3) << 1;        // even batch of the pair
        const int p = yy * NCP + b;
        union { __half2 h[2]; float2 f; } u;
        u.h[0] = __floats2half2_rn(re[p] * scale,     im[p] * scale);
        u.h[1] = __floats2half2_rn(re[p + 1] * scale, im[p + 1] * scale);
        // float2 slot index: ((yy*512+x)*8 + b) half2's / 2
        ghat_f2[((size_t)yy * GXD + x) * 4 + (b >> 1)] = u.f;
    }
}

// Kernel C: 7x7 KB gather on fp16 interleaved ghat.
// Block = 32 samples x 8 batches; per tap the 8 b-lanes read one 32 B segment;
// the 7 x-taps of a row are 224 contiguous bytes (x-consecutive by construction).
__global__ __launch_bounds__(256) void gather_kernel(
    const __half2* __restrict__ gh,
    const float* __restrict__ wy, const float* __restrict__ wx,
    const float* __restrict__ phr, const float* __restrict__ phi,
    const int* __restrict__ iy, const int* __restrict__ ix,
    float2* __restrict__ out)
{
    __shared__ int   s_iy[32 * JD];
    __shared__ int   s_ix[32 * JD];
    __shared__ float s_wy[32 * JD];
    __shared__ float s_wx[32 * JD];
    __shared__ float s_pr[32];
    __shared__ float s_pi[32];
    const int t = threadIdx.x;
    const int n0 = blockIdx.x * 32;

    if (t < 224) {                           // 32 samples x 7 taps, coalesced
        const int g = n0 * JD + t;
        s_iy[t] = iy[g];
        s_ix[t] = ix[g];
        s_wy[t] = wy[g];
        s_wx[t] = wx[g];
    } else {                                 // threads 224..255: phase
        const int s = t - 224;
        s_pr[s] = phr[n0 + s];
        s_pi[s] = phi[n0 + s];
    }
    __syncthreads();

    const int b = t & 7;
    const int s = t >> 3;                    // local sample 0..31
    const int base = s * JD;

    int iyl[JD], ixl[JD];
    float wyl[JD], wxl[JD];
    #pragma unroll
    for (int j = 0; j < JD; ++j) {
        iyl[j] = s_iy[base + j];
        ixl[j] = s_ix[base + j];
        wyl[j] = s_wy[base + j];
        wxl[j] = s_wx[base + j];
    }

    float ar = 0.0f, ai = 0.0f;
    #pragma unroll
    for (int j = 0; j < JD; ++j) {
        const int rowoff = iyl[j] * GXD;
        const float wj = wyl[j];
        #pragma unroll
        for (int k = 0; k < JD; ++k) {
            const float w = wj * wxl[k];
            const float2 v = __half22float2(gh[(size_t)(rowoff + ixl[k]) * BD + b]);
            ar += v.x * w;
            ai += v.y * w;
        }
    }

    const int n = n0 + s;
    const float pr = s_pr[s], pi = s_pi[s];
    out[(size_t)b * NSAMP + n] = make_float2(ar * pr - ai * pi,
                                             ar * pi + ai * pr);
}

extern "C" void kernel_launch(void* const* d_in, const int* in_sizes, int n_in,
                              void* d_out, int out_size, void* d_ws, size_t ws_size,
                              hipStream_t stream) {
    const float* xr   = (const float*)d_in[0];
    const float* xi   = (const float*)d_in[1];
    const float* sc_y = (const float*)d_in[2];
    const float* sc_x = (const float*)d_in[3];
    const float* wy   = (const float*)d_in[4];
    const float* wx   = (const float*)d_in[5];
    const float* phr  = (const float*)d_in[6];
    const float* phi  = (const float*)d_in[7];
    const int*   iy   = (const int*)d_in[8];
    const int*   ix   = (const int*)d_in[9];

    // Workspace: G1i (8.39 MB fp32 interleaved) | ghat fp16 (8.39 MB interleaved)
    char* ws = (char*)d_ws;
    float4*  G1i4 = (float4*)ws;
    __half2* gh   = (__half2*)(ws + (size_t)HD * GXD * BD * sizeof(float2));

    rowfft_kernel<<<HD, 512, 0, stream>>>(xr, xi, sc_y, sc_x, G1i4);
    colfft_kernel<<<GXD, 512, 0, stream>>>(G1i4, (float2*)gh);
    gather_kernel<<<NSAMP / 32, 256, 0, stream>>>(
        gh, wy, wx, phr, phi, iy, ix, (float2*)d_out);
}